// Round 6
// baseline (9785.284 us; speedup 1.0000x reference)
//
#include <hip/hip_runtime.h>

typedef __attribute__((ext_vector_type(8))) short short8;
typedef __attribute__((ext_vector_type(4))) float f32x4;
typedef unsigned short u16;
typedef unsigned int u32;

// ---------------- workspace layout (bytes) ----------------
// xb:  [512][64][512] bf16                                = 33,554,432
// h0h: [513 slot][4 g][128 cu][16 b][8 u] bf16 (s=t+1)    = 67,239,936
// h1h: same                                                = 67,239,936
// f0/f1: [4 g][128 cu] monotonic step flags, 32B stride    = 16,384 each
#define XB_OFF 0ul
#define H0_OFF 33554432ul
#define H1_OFF 100794368ul
#define F0_OFF 168034304ul
#define F1_OFF 168050688ul
#define FLAGS_LEN 32768ul

// ---------------- LDS layout (bytes) ----------------
#define WB_MAX    131072                  // 32 cols * 2*K bytes (K=2048 for L1)
#define GATES_OFF WB_MAX                  // [16][33] f32 = 2112
#define CST_OFF   (WB_MAX + 2112)         // [4][16][8] f32 = 2048
#define BIAS_OFF  (WB_MAX + 2112 + 2048)  // [32] f32 = 128
#define LDS_TOTAL (WB_MAX + 2112 + 2048 + 128)   // 135360 <= 163840

__device__ __forceinline__ u16 f2bf(float f) {
  u32 u = __float_as_uint(f);
  return (u16)((u + 0x7fffu + ((u >> 16) & 1u)) >> 16);   // RNE
}
__device__ __forceinline__ float bf2f(u16 s) { return __uint_as_float(((u32)s) << 16); }

__device__ __forceinline__ u32 load_sc01(const u32* p) {
  u32 v;
  asm volatile("global_load_dword %0, %1, off sc0 sc1\n\ts_waitcnt vmcnt(0)"
               : "=v"(v) : "v"(p) : "memory");
  return v;
}
__device__ __forceinline__ void store_sc01(u32* p, u32 v) {
  asm volatile("global_store_dword %0, %1, off sc0 sc1" :: "v"(p), "v"(v) : "memory");
}

// x[b][t][i] fp32 -> xb[t][b][i] bf16
__global__ __launch_bounds__(256) void prep_x(const float* __restrict__ x,
                                              u16* __restrict__ xb) {
  u32 stride = gridDim.x * blockDim.x;
  for (u32 e = blockIdx.x * blockDim.x + threadIdx.x; e < 16777216u; e += stride) {
    u32 i = e & 511u, b = (e >> 9) & 63u, t = e >> 15;
    xb[e] = f2bf(x[((size_t)b << 18) + ((size_t)t << 9) + i]);
  }
}

// Persistent kernel, 256 blocks (1/CU). Blocks 0..127: layer0. Blocks 128..255:
// layer1 (one step behind). Batch is split into 4 independent groups of 16; each
// round processes g=0..3 sequentially, so group g's cross-CU h exchange has ~3
// slots of other groups' compute to hide in (latency-hiding by interleaving).
__global__ __launch_bounds__(256, 1) void lstm_persist(
    const u16* __restrict__ xb,
    const float* __restrict__ wih0, const float* __restrict__ whh0,
    const float* __restrict__ bih0, const float* __restrict__ bhh0,
    const float* __restrict__ wih1, const float* __restrict__ whh1,
    const float* __restrict__ bih1, const float* __restrict__ bhh1,
    u16* __restrict__ h0h, u16* __restrict__ h1h,
    u32* __restrict__ f0, u32* __restrict__ f1,
    const float* __restrict__ fc_w, const float* __restrict__ fc_b,
    float* __restrict__ out) {
  extern __shared__ char smem[];
  float* gates = (float*)(smem + GATES_OFF);  // [16][33]
  float* cst   = (float*)(smem + CST_OFF);    // [4][16][8]
  float* bias  = (float*)(smem + BIAS_OFF);   // [32]

  const int cu = blockIdx.x;
  const int layer = cu >> 7;
  const int lcu = cu & 127;
  const int U0 = lcu * 8;
  const int K2 = layer ? 4096 : 3072;         // bytes per LDS weight column
  const int tid = threadIdx.x;

  // ---- startup: pack weight columns; swizzle (n&7)<<4 -> 16B bank-slot spread
  for (int n = 0; n < 32; ++n) {
    const int grow = (n >> 3) * 1024 + U0 + (n & 7);
    char* colbase = smem + n * K2;
    const u32 swn = (u32)(n & 7) << 4;
    if (!layer) {
      const float* rih = wih0 + (size_t)grow * 512;
      const float* rhh = whh0 + (size_t)grow * 1024;
      for (int k = tid; k < 1536; k += 256) {
        float v = (k < 512) ? rih[k] : rhh[k - 512];
        *(u16*)(colbase + (((u32)k * 2u) ^ swn)) = f2bf(v);
      }
    } else {
      const float* rih = wih1 + (size_t)grow * 1024;
      const float* rhh = whh1 + (size_t)grow * 1024;
      for (int k = tid; k < 2048; k += 256) {
        float v = (k < 1024) ? rih[k] : rhh[k - 1024];
        *(u16*)(colbase + (((u32)k * 2u) ^ swn)) = f2bf(v);
      }
    }
  }
  if (tid < 32) {
    int grow = (tid >> 3) * 1024 + U0 + (tid & 7);
    bias[tid] = layer ? (bih1[grow] + bhh1[grow]) : (bih0[grow] + bhh0[grow]);
  }
  for (int i = tid; i < 512; i += 256) cst[i] = 0.0f;
  for (int i = tid; i < 528; i += 256) gates[i] = 0.0f;
  __syncthreads();

  const int lane = tid & 63;
  const int wave = tid >> 6;
  const int lr = lane & 15;
  const int lq = lane >> 4;
  const int lkel = lq * 8;
  const u32 swz = (u32)(lr & 7) << 4;
  const char* wrow0 = smem + (size_t)lr * K2;
  const char* wrow1 = smem + (size_t)(16 + lr) * K2;

  // this wave's 32 producer flags: c = 4*wave + 16*((lane&31)>>2) + (lane&3)
  const u32 myc = (u32)(4 * wave + 16 * ((lane & 31) >> 2) + (lane & 3));

  auto wpoll = [&](const u32* fbase, u32 target) {   // fbase = flag array for group g
    const u32* p = fbase + myc * 8u;                 // 32B stride
    for (;;) {
      u32 v = load_sc01(p);
      if (__all((int)(v >= target))) break;
      __builtin_amdgcn_s_sleep(1);
    }
  };

  for (int t = 0; t < 512; ++t) {
    for (int g = 0; g < 4; ++g) {
      f32x4 z = {0.0f, 0.0f, 0.0f, 0.0f};
      f32x4 acc0 = z, acc1 = z;
      short8 A[16];

      auto mfma2 = [&](short8 a, int k0) {
        const u32 kb = ((u32)(k0 + lkel) * 2u) ^ swz;
        short8 b0 = *(const short8*)(wrow0 + kb);
        short8 b1 = *(const short8*)(wrow1 + kb);
        acc0 = __builtin_amdgcn_mfma_f32_16x16x32_bf16(a, b0, acc0, 0, 0, 0);
        acc1 = __builtin_amdgcn_mfma_f32_16x16x32_bf16(a, b1, acc1, 0, 0, 0);
      };

      if (!layer) {
        // x-part loads first (no dependency), then poll + h loads, then MFMA sweep
        const u16* Ax = xb + (size_t)t * 32768 + (size_t)(g * 16 + lr) * 512 + lkel;
        #pragma unroll
        for (int j = 0; j < 4; ++j) A[j] = *(const short8*)(Ax + (wave + 4 * j) * 32);
        if (t > 0) {
          wpoll(f0 + (size_t)g * 1024, (u32)t);
          const u16* Hb = h0h + (size_t)t * 65536 + (size_t)g * 16384 + (size_t)lr * 8;
          #pragma unroll
          for (int j = 0; j < 8; ++j)
            A[4 + j] = *(const short8*)(Hb + (size_t)(4 * wave + 16 * j + lq) * 128);
        }
        #pragma unroll
        for (int j = 0; j < 4; ++j) mfma2(A[j], (wave + 4 * j) * 32);
        if (t > 0) {
          #pragma unroll
          for (int j = 0; j < 8; ++j) mfma2(A[4 + j], (wave + 4 * (4 + j)) * 32);
        }
      } else {
        if (t > 0) {
          wpoll(f1 + (size_t)g * 1024, (u32)t);     // h1(t-1): published 4 slots ago
          const u16* Hb1 = h1h + (size_t)t * 65536 + (size_t)g * 16384 + (size_t)lr * 8;
          #pragma unroll
          for (int j = 0; j < 8; ++j)
            A[j] = *(const short8*)(Hb1 + (size_t)(4 * wave + 16 * j + lq) * 128);
        }
        wpoll(f0 + (size_t)g * 1024, (u32)(t + 1)); // h0(t): fresh dependency
        const u16* Hb0 = h0h + (size_t)(t + 1) * 65536 + (size_t)g * 16384 + (size_t)lr * 8;
        #pragma unroll
        for (int j = 0; j < 8; ++j)
          A[8 + j] = *(const short8*)(Hb0 + (size_t)(4 * wave + 16 * j + lq) * 128);
        if (t > 0) {
          #pragma unroll
          for (int j = 0; j < 8; ++j) mfma2(A[j], (wave + 4 * (8 + j)) * 32);
        }
        #pragma unroll
        for (int j = 0; j < 8; ++j) mfma2(A[8 + j], (wave + 4 * j) * 32);
      }

      // K-split reduction across 4 waves via LDS float atomics
      #pragma unroll
      for (int r = 0; r < 4; ++r) {
        atomicAdd(&gates[(lq * 4 + r) * 33 + lr],      acc0[r]);
        atomicAdd(&gates[(lq * 4 + r) * 33 + 16 + lr], acc1[r]);
      }
      __syncthreads();

      if (tid < 64) { // nonlinearity + state for this group (wave 0 only)
        const int b = tid >> 2;              // batch within group
        const int ub = (tid & 3) * 2;
        float* cs = cst + g * 128 + b * 8;
        float hv[2];
        #pragma unroll
        for (int du = 0; du < 2; ++du) {
          const int u = ub + du;
          float gi = gates[b * 33 + u];       gates[b * 33 + u] = 0.0f;
          float gf = gates[b * 33 + 8 + u];   gates[b * 33 + 8 + u] = 0.0f;
          float gg = gates[b * 33 + 16 + u];  gates[b * 33 + 16 + u] = 0.0f;
          float go = gates[b * 33 + 24 + u];  gates[b * 33 + 24 + u] = 0.0f;
          gi += bias[u]; gf += bias[8 + u]; gg += bias[16 + u]; go += bias[24 + u];
          float ii = 1.0f / (1.0f + __expf(-gi));
          float ff = 1.0f / (1.0f + __expf(-gf));
          float g2 = 1.0f - 2.0f / (__expf(2.0f * gg) + 1.0f);
          float oo = 1.0f / (1.0f + __expf(-go));
          float c = ff * cs[u] + ii * g2;
          cs[u] = c;
          hv[du] = oo * (1.0f - 2.0f / (__expf(2.0f * c) + 1.0f));
        }
        u32 packed = (u32)f2bf(hv[0]) | ((u32)f2bf(hv[1]) << 16);
        u16* hist = layer ? h1h : h0h;
        u32* dst = (u32*)(hist + (size_t)(t + 1) * 65536 + (size_t)g * 16384
                          + ((size_t)lcu << 7)) + tid;
        store_sc01(dst, packed);
      }
      __syncthreads();             // gates re-zeroed; other waves may proceed
      if (tid == 0) {              // wave 0: drain own h stores, publish flag
        asm volatile("s_waitcnt vmcnt(0)" ::: "memory");
        u32* fl = (layer ? f1 : f0) + ((size_t)g * 128 + (size_t)lcu) * 8;
        store_sc01(fl, (u32)(t + 1));
      }
    }
  }

  // FC + softmax epilogue on block 0 (reads h1[511] = slot 512)
  if (cu == 0) {
    if (wave == 0) {               // 512 flags, 8 per lane
      #pragma unroll
      for (int j = 0; j < 8; ++j) {
        const u32* p = f1 + (u32)(lane + 64 * j) * 8u;
        while (load_sc01(p) < 512u) __builtin_amdgcn_s_sleep(1);
      }
    }
    __syncthreads();
    if (tid < 128) {
      const int b = tid >> 1, cls = tid & 1;
      const u16* hbase = h1h + (size_t)512 * 65536 + (size_t)(b >> 4) * 16384
                         + (size_t)(b & 15) * 8;
      const float* w = fc_w + (size_t)cls * 1024;
      float sum = fc_b[cls];
      for (int c = 0; c < 128; ++c) {
        short8 hvv = *(const short8*)(hbase + (size_t)c * 128);
        #pragma unroll
        for (int e = 0; e < 8; ++e) sum += bf2f((u16)hvv[e]) * w[c * 8 + e];
      }
      float other = __shfl_xor(sum, 1);
      float mx = fmaxf(sum, other);
      float e0 = __expf(sum - mx), e1 = __expf(other - mx);
      out[b * 2 + cls] = e0 / (e0 + e1);
    }
  }
}

extern "C" void kernel_launch(void* const* d_in, const int* in_sizes, int n_in,
                              void* d_out, int out_size, void* d_ws, size_t ws_size,
                              hipStream_t stream) {
  const float* x    = (const float*)d_in[0];
  const float* wih0 = (const float*)d_in[1];
  const float* whh0 = (const float*)d_in[2];
  const float* bih0 = (const float*)d_in[3];
  const float* bhh0 = (const float*)d_in[4];
  const float* wih1 = (const float*)d_in[5];
  const float* whh1 = (const float*)d_in[6];
  const float* bih1 = (const float*)d_in[7];
  const float* bhh1 = (const float*)d_in[8];
  const float* fcw  = (const float*)d_in[9];
  const float* fcb  = (const float*)d_in[10];
  float* out = (float*)d_out;
  char* ws = (char*)d_ws;

  u16* xb  = (u16*)(ws + XB_OFF);
  u16* h0h = (u16*)(ws + H0_OFF);
  u16* h1h = (u16*)(ws + H1_OFF);
  u32* f0  = (u32*)(ws + F0_OFF);
  u32* f1  = (u32*)(ws + F1_OFF);

  (void)hipFuncSetAttribute((const void*)lstm_persist,
      hipFuncAttributeMaxDynamicSharedMemorySize, LDS_TOTAL);

  hipMemsetAsync(ws + F0_OFF, 0, FLAGS_LEN, stream);   // zero step flags
  prep_x<<<8192, 256, 0, stream>>>(x, xb);
  lstm_persist<<<256, 256, LDS_TOTAL, stream>>>(
      (const u16*)xb, wih0, whh0, bih0, bhh0, wih1, whh1, bih1, bhh1,
      h0h, h1h, f0, f1, fcw, fcb, out);
}

// Round 7
// 8516.902 us; speedup vs baseline: 1.1489x; 1.1489x over previous
//
#include <hip/hip_runtime.h>

typedef __attribute__((ext_vector_type(8))) short short8;
typedef __attribute__((ext_vector_type(4))) float f32x4;
typedef unsigned short u16;
typedef unsigned int u32;

// ---------------- workspace layout (bytes) ----------------
// xb:  [512][64][512] bf16                          = 33,554,432
// h0h: [513][128 cu][64 b][8 u] bf16 (slot t+1=h[t])= 67,239,936
// h1h: same                                          = 67,239,936
// f0/f1: [128 cu][4 wave] step flags, 32B stride     = 16,384 each
#define XB_OFF 0ul
#define H0_OFF 33554432ul
#define H1_OFF 100794368ul
#define F0_OFF 168034304ul
#define F1_OFF 168050688ul
#define FLAGS_LEN 32768ul

// ---------------- LDS layout (bytes) ----------------
#define WB_MAX    131072                  // 32 cols * 2*K bytes (K=2048 for L1)
#define GATES_OFF WB_MAX                  // [64][33] f32 = 8448 (pad vs bank conflicts)
#define CST_OFF   (WB_MAX + 8448)         // [64][8]  f32 = 2048
#define BIAS_OFF  (WB_MAX + 8448 + 2048)  // [32] f32 = 128
#define LDS_TOTAL (WB_MAX + 8448 + 2048 + 128)   // 141696 <= 163840

__device__ __forceinline__ u16 f2bf(float f) {
  u32 u = __float_as_uint(f);
  return (u16)((u + 0x7fffu + ((u >> 16) & 1u)) >> 16);   // RNE
}
__device__ __forceinline__ float bf2f(u16 s) { return __uint_as_float(((u32)s) << 16); }

__device__ __forceinline__ u32 load_sc01(const u32* p) {
  u32 v;
  asm volatile("global_load_dword %0, %1, off sc0 sc1\n\ts_waitcnt vmcnt(0)"
               : "=v"(v) : "v"(p) : "memory");
  return v;
}
__device__ __forceinline__ void store_sc01(u32* p, u32 v) {
  asm volatile("global_store_dword %0, %1, off sc0 sc1" :: "v"(p), "v"(v) : "memory");
}

// x[b][t][i] fp32 -> xb[t][b][i] bf16
__global__ __launch_bounds__(256) void prep_x(const float* __restrict__ x,
                                              u16* __restrict__ xb) {
  u32 stride = gridDim.x * blockDim.x;
  for (u32 e = blockIdx.x * blockDim.x + threadIdx.x; e < 16777216u; e += stride) {
    u32 i = e & 511u, b = (e >> 9) & 63u, t = e >> 15;
    xb[e] = f2bf(x[((size_t)b << 18) + ((size_t)t << 9) + i]);
  }
}

// Persistent kernel, 256 blocks (1/CU). Blocks 0..127: layer0 (K=1536 = [x|h0prev]).
// Blocks 128..255: layer1 (K=2048 = [h0cur|h1prev]).
// Publish path is barrier-free: each wave stores its h quarter (sc0sc1), drains
// its OWN stores, stores its own per-wave flag. Consumers poll (chunk x wave)
// flags with two independent pipelined loads; tight spin (no s_sleep).
__global__ __launch_bounds__(256, 1) void lstm_persist(
    const u16* __restrict__ xb,
    const float* __restrict__ wih0, const float* __restrict__ whh0,
    const float* __restrict__ bih0, const float* __restrict__ bhh0,
    const float* __restrict__ wih1, const float* __restrict__ whh1,
    const float* __restrict__ bih1, const float* __restrict__ bhh1,
    u16* __restrict__ h0h, u16* __restrict__ h1h,
    u32* __restrict__ f0, u32* __restrict__ f1,
    const float* __restrict__ fc_w, const float* __restrict__ fc_b,
    float* __restrict__ out) {
  extern __shared__ char smem[];
  float* gates = (float*)(smem + GATES_OFF);  // [64][33]
  float* cst   = (float*)(smem + CST_OFF);    // [64][8]
  float* bias  = (float*)(smem + BIAS_OFF);   // [32]

  const int cu = blockIdx.x;
  const int layer = cu >> 7;
  const int lcu = cu & 127;
  const int U0 = lcu * 8;
  const int K2 = layer ? 4096 : 3072;         // bytes per LDS weight column
  const int tid = threadIdx.x;

  // ---- startup: pack weight columns; swizzle (n&7)<<4 -> 16B bank-slot spread
  for (int n = 0; n < 32; ++n) {
    const int grow = (n >> 3) * 1024 + U0 + (n & 7);
    char* colbase = smem + n * K2;
    const u32 swn = (u32)(n & 7) << 4;
    if (!layer) {
      const float* rih = wih0 + (size_t)grow * 512;
      const float* rhh = whh0 + (size_t)grow * 1024;
      for (int k = tid; k < 1536; k += 256) {
        float v = (k < 512) ? rih[k] : rhh[k - 512];
        *(u16*)(colbase + (((u32)k * 2u) ^ swn)) = f2bf(v);
      }
    } else {
      const float* rih = wih1 + (size_t)grow * 1024;
      const float* rhh = whh1 + (size_t)grow * 1024;
      for (int k = tid; k < 2048; k += 256) {
        float v = (k < 1024) ? rih[k] : rhh[k - 1024];
        *(u16*)(colbase + (((u32)k * 2u) ^ swn)) = f2bf(v);
      }
    }
  }
  if (tid < 32) {
    int grow = (tid >> 3) * 1024 + U0 + (tid & 7);
    bias[tid] = layer ? (bih1[grow] + bhh1[grow]) : (bih0[grow] + bhh0[grow]);
  }
  for (int i = tid; i < 512; i += 256) cst[i] = 0.0f;
  for (int i = tid; i < 2112; i += 256) gates[i] = 0.0f;
  __syncthreads();

  const int lane = tid & 63;
  const int wave = tid >> 6;
  const int lr = lane & 15;
  const int lq = lane >> 4;
  const int lkel = lq * 8;
  const u32 swz = (u32)(lr & 7) << 4;
  const char* wrow0 = smem + (size_t)lr * K2;
  const char* wrow1 = smem + (size_t)(16 + lr) * K2;

  // this wave's 32 producer chunks: c = 4*wave + 16*((lane&31)>>2) + (lane&3)
  const u32 myc = (u32)(4 * wave + 16 * ((lane & 31) >> 2) + (lane & 3));

  // wait until all 4 per-wave flags of all 32 chunks reach target.
  // lane covers chunk=myc, producer-waves {lane>>5, (lane>>5)+2}: two
  // independent loads pipelined in one round trip.
  auto wpoll = [&](const u32* fbase, u32 target) {
    const u32* p1 = fbase + (myc * 4u + (u32)(lane >> 5)) * 8u;
    const u32* p2 = p1 + 16u;
    for (;;) {
      u32 v1, v2;
      asm volatile("global_load_dword %0, %2, off sc0 sc1\n\t"
                   "global_load_dword %1, %3, off sc0 sc1\n\t"
                   "s_waitcnt vmcnt(0)"
                   : "=v"(v1), "=v"(v2) : "v"(p1), "v"(p2) : "memory");
      if (__all((int)((v1 >= target) & (v2 >= target)))) break;
    }
  };

  for (int t = 0; t < 512; ++t) {
    f32x4 z = {0.0f, 0.0f, 0.0f, 0.0f};
    f32x4 acc[4][2];
    #pragma unroll
    for (int a = 0; a < 4; ++a) { acc[a][0] = z; acc[a][1] = z; }

    short8 A[12][4];           // A-fragment register file (SROA'd; static idx only)

    auto load_x = [&](int s, const u16* Abase, int k0) {
      const u16* ap = Abase + (size_t)lr * 512 + k0 + lkel;
      A[s][0] = *(const short8*)(ap);
      A[s][1] = *(const short8*)(ap + 16 * 512);
      A[s][2] = *(const short8*)(ap + 32 * 512);
      A[s][3] = *(const short8*)(ap + 48 * 512);
    };
    auto load_h = [&](int s, const u16* Hbase, int c_base) {
      const u16* ap = Hbase + ((size_t)(c_base + lq) << 9) + (size_t)lr * 8;
      A[s][0] = *(const short8*)(ap);
      A[s][1] = *(const short8*)(ap + 128);
      A[s][2] = *(const short8*)(ap + 256);
      A[s][3] = *(const short8*)(ap + 384);
    };
    auto mfma_tile = [&](int s, int k0) {
      const u32 kb = ((u32)(k0 + lkel) * 2u) ^ swz;
      short8 b0 = *(const short8*)(wrow0 + kb);
      short8 b1 = *(const short8*)(wrow1 + kb);
      acc[0][0] = __builtin_amdgcn_mfma_f32_16x16x32_bf16(A[s][0], b0, acc[0][0], 0, 0, 0);
      acc[1][0] = __builtin_amdgcn_mfma_f32_16x16x32_bf16(A[s][1], b0, acc[1][0], 0, 0, 0);
      acc[2][0] = __builtin_amdgcn_mfma_f32_16x16x32_bf16(A[s][2], b0, acc[2][0], 0, 0, 0);
      acc[3][0] = __builtin_amdgcn_mfma_f32_16x16x32_bf16(A[s][3], b0, acc[3][0], 0, 0, 0);
      acc[0][1] = __builtin_amdgcn_mfma_f32_16x16x32_bf16(A[s][0], b1, acc[0][1], 0, 0, 0);
      acc[1][1] = __builtin_amdgcn_mfma_f32_16x16x32_bf16(A[s][1], b1, acc[1][1], 0, 0, 0);
      acc[2][1] = __builtin_amdgcn_mfma_f32_16x16x32_bf16(A[s][2], b1, acc[2][1], 0, 0, 0);
      acc[3][1] = __builtin_amdgcn_mfma_f32_16x16x32_bf16(A[s][3], b1, acc[3][1], 0, 0, 0);
    };

    if (!layer) {
      const u16* Ax = xb + (size_t)t * 32768;
      #pragma unroll
      for (int j = 0; j < 4; ++j) load_x(j, Ax, (wave + 4 * j) * 32);
      if (t > 0) {
        wpoll(f0, (u32)t);
        const u16* Hs = h0h + (size_t)t * 65536;       // h0[t-1]
        #pragma unroll
        for (int j = 4; j < 12; ++j) load_h(j, Hs, 4 * wave + 16 * (j - 4));
      }
      #pragma unroll
      for (int j = 0; j < 4; ++j) mfma_tile(j, (wave + 4 * j) * 32);
      if (t > 0) {
        #pragma unroll
        for (int j = 4; j < 12; ++j) mfma_tile(j, (wave + 4 * j) * 32);
      }
    } else {
      if (t > 0) {
        wpoll(f1, (u32)t);
        const u16* H1s = h1h + (size_t)t * 65536;      // h1[t-1]
        #pragma unroll
        for (int j = 0; j < 8; ++j) load_h(j, H1s, 4 * wave + 16 * j);
      }
      wpoll(f0, (u32)(t + 1));
      const u16* H0s = h0h + (size_t)(t + 1) * 65536;  // h0[t]
      #pragma unroll
      for (int j = 0; j < 4; ++j) load_h(8 + j, H0s, 4 * wave + 16 * j);
      if (t > 0) {
        #pragma unroll
        for (int j = 0; j < 8; ++j) mfma_tile(j, (wave + 4 * (8 + j)) * 32);
      }
      #pragma unroll
      for (int j = 0; j < 4; ++j) load_h(j, H0s, 4 * wave + 16 * (4 + j));  // reuse slots
      #pragma unroll
      for (int j = 0; j < 4; ++j) mfma_tile(8 + j, (wave + 4 * j) * 32);
      #pragma unroll
      for (int j = 0; j < 4; ++j) mfma_tile(j, (wave + 4 * (4 + j)) * 32);
    }

    __syncthreads();   // bar1: prev step's gate reads/rezeros done in all waves

    // K-split reduction across 4 waves via LDS float atomics (stride 33)
    #pragma unroll
    for (int mt = 0; mt < 4; ++mt)
      #pragma unroll
      for (int nt = 0; nt < 2; ++nt)
        #pragma unroll
        for (int r = 0; r < 4; ++r) {
          int row = mt * 16 + lq * 4 + r;              // batch
          int col = nt * 16 + lr;                      // local gate col
          atomicAdd(&gates[row * 33 + col], acc[mt][nt][r]);
        }
    __syncthreads();   // bar2: all contributions in

    { // nonlinearity + state; rezero own slots; barrier-free publish tail
      const int b = tid >> 2;
      const int ub = (tid & 3) * 2;
      float hv[2];
      #pragma unroll
      for (int du = 0; du < 2; ++du) {
        const int u = ub + du;
        float gi = gates[b * 33 + u];       gates[b * 33 + u] = 0.0f;
        float gf = gates[b * 33 + 8 + u];   gates[b * 33 + 8 + u] = 0.0f;
        float gg = gates[b * 33 + 16 + u];  gates[b * 33 + 16 + u] = 0.0f;
        float go = gates[b * 33 + 24 + u];  gates[b * 33 + 24 + u] = 0.0f;
        gi += bias[u]; gf += bias[8 + u]; gg += bias[16 + u]; go += bias[24 + u];
        float ii = 1.0f / (1.0f + __expf(-gi));
        float ff = 1.0f / (1.0f + __expf(-gf));
        float g2 = 1.0f - 2.0f / (__expf(2.0f * gg) + 1.0f);
        float oo = 1.0f / (1.0f + __expf(-go));
        float c = ff * cst[b * 8 + u] + ii * g2;
        cst[b * 8 + u] = c;
        hv[du] = oo * (1.0f - 2.0f / (__expf(2.0f * c) + 1.0f));
      }
      u32 packed = (u32)f2bf(hv[0]) | ((u32)f2bf(hv[1]) << 16);
      u16* hist = layer ? h1h : h0h;
      u32* dst = (u32*)(hist + (size_t)(t + 1) * 65536 + ((size_t)lcu << 9)) + tid;
      store_sc01(dst, packed);
      asm volatile("s_waitcnt vmcnt(0)" ::: "memory");  // own wave's h stores ack'd
      if ((tid & 63) == 0) {                            // per-wave flag, no barrier
        u32* fl = (layer ? f1 : f0) + ((u32)lcu * 4u + (u32)wave) * 8u;
        store_sc01(fl, (u32)(t + 1));
      }
    }
  }

  // FC + softmax epilogue on block 0 (reads h1[511] = slot 512)
  if (cu == 0) {
    if (wave == 0) {               // 512 L1 flags, 8 per lane
      #pragma unroll
      for (int j = 0; j < 8; ++j) {
        const u32* p = f1 + (u32)(lane + 64 * j) * 8u;
        while (load_sc01(p) < 512u) { }
      }
    }
    __syncthreads();
    if (tid < 128) {
      const int b = tid >> 1, cls = tid & 1;
      const u16* hbase = h1h + (size_t)512 * 65536;
      const float* w = fc_w + (size_t)cls * 1024;
      float sum = fc_b[cls];
      for (int c = 0; c < 128; ++c) {
        short8 hvv = *(const short8*)(hbase + ((size_t)c << 9) + (size_t)b * 8);
        #pragma unroll
        for (int e = 0; e < 8; ++e) sum += bf2f((u16)hvv[e]) * w[c * 8 + e];
      }
      float other = __shfl_xor(sum, 1);
      float mx = fmaxf(sum, other);
      float e0 = __expf(sum - mx), e1 = __expf(other - mx);
      out[b * 2 + cls] = e0 / (e0 + e1);
    }
  }
}

extern "C" void kernel_launch(void* const* d_in, const int* in_sizes, int n_in,
                              void* d_out, int out_size, void* d_ws, size_t ws_size,
                              hipStream_t stream) {
  const float* x    = (const float*)d_in[0];
  const float* wih0 = (const float*)d_in[1];
  const float* whh0 = (const float*)d_in[2];
  const float* bih0 = (const float*)d_in[3];
  const float* bhh0 = (const float*)d_in[4];
  const float* wih1 = (const float*)d_in[5];
  const float* whh1 = (const float*)d_in[6];
  const float* bih1 = (const float*)d_in[7];
  const float* bhh1 = (const float*)d_in[8];
  const float* fcw  = (const float*)d_in[9];
  const float* fcb  = (const float*)d_in[10];
  float* out = (float*)d_out;
  char* ws = (char*)d_ws;

  u16* xb  = (u16*)(ws + XB_OFF);
  u16* h0h = (u16*)(ws + H0_OFF);
  u16* h1h = (u16*)(ws + H1_OFF);
  u32* f0  = (u32*)(ws + F0_OFF);
  u32* f1  = (u32*)(ws + F1_OFF);

  (void)hipFuncSetAttribute((const void*)lstm_persist,
      hipFuncAttributeMaxDynamicSharedMemorySize, LDS_TOTAL);

  hipMemsetAsync(ws + F0_OFF, 0, FLAGS_LEN, stream);   // zero step flags
  prep_x<<<8192, 256, 0, stream>>>(x, xb);
  lstm_persist<<<256, 256, LDS_TOTAL, stream>>>(
      (const u16*)xb, wih0, whh0, bih0, bhh0, wih1, whh1, bih1, bhh1,
      h0h, h1h, f0, f1, fcw, fcb, out);
}